// Round 2
// baseline (619.818 us; speedup 1.0000x reference)
//
#include <hip/hip_runtime.h>
#include <hip/hip_bf16.h>

// Monarch block-MLP fused, bf16 MFMA, fp32 accumulate. Round 2:
//  - x pre-cast to bf16 (removes fp32->bf16 VALU glue from stage-A critical path)
//  - __launch_bounds__(512,2): let the allocator use up to 256 regs for deep
//    load pipelining (round 1 pinned itself at 124 regs / ~4 loads in flight)
//  - LDS y0 buffer [32][17][36] + paired b32 writes (4-way) + b64 reads (floor)

typedef __attribute__((ext_vector_type(8))) short short8;
typedef __attribute__((ext_vector_type(4))) short short4v;
typedef __attribute__((ext_vector_type(4))) float floatx4;

__device__ __forceinline__ unsigned short f2bf(float f) {
    unsigned int u = __float_as_uint(f);
    unsigned int r = 0x7FFFu + ((u >> 16) & 1u);
    return (unsigned short)((u + r) >> 16);
}
__device__ __forceinline__ short8 ld8(const unsigned short* p) {
    return *reinterpret_cast<const short8*>(p);
}

// x fp32 -> bf16, 8 elems/thread
__global__ void cast_x_bf16(const float* __restrict__ in,
                            unsigned short* __restrict__ out, int n8) {
    int stride = gridDim.x * blockDim.x;
    for (int idx = blockIdx.x * blockDim.x + threadIdx.x; idx < n8; idx += stride) {
        const float* p = in + (size_t)idx * 8;
        floatx4 f0 = *reinterpret_cast<const floatx4*>(p);
        floatx4 f1 = *reinterpret_cast<const floatx4*>(p + 4);
        short8 o;
#pragma unroll
        for (int j = 0; j < 4; ++j) {
            o[j]     = (short)f2bf(f0[j]);
            o[j + 4] = (short)f2bf(f1[j]);
        }
        *reinterpret_cast<short8*>(out + (size_t)idx * 8) = o;
    }
}

// out[b][c][r] = bf16(in[b][r][c])
__global__ void transpose_cast_k(const float* __restrict__ in,
                                 unsigned short* __restrict__ out,
                                 int Bn, int R, int C) {
    int total = Bn * R * C;
    int stride = gridDim.x * blockDim.x;
    for (int idx = blockIdx.x * blockDim.x + threadIdx.x; idx < total; idx += stride) {
        int rc = R * C;
        int b = idx / rc;
        int rem = idx - b * rc;
        int c = rem / R;
        int r = rem - c * R;
        out[idx] = f2bf(in[(size_t)(b * R + r) * C + c]);
    }
}

// MFMA 16x16x32 bf16 layouts (m89-verified):
//   A: row = lane&15, k = (lane>>4)*8 + i ;  B: col = lane&15, same k
//   D: col = lane&15, row = (lane>>4)*4 + reg
template<int KB, int SN, bool ELU, bool XBF16>
__global__ __launch_bounds__(512, 2) void fused2(
    const float* __restrict__ xf,             // fp32 input (fallback path)
    const unsigned short* __restrict__ xb,    // bf16 input
    const unsigned short* __restrict__ wat,   // [KB][SN][64] bf16
    const unsigned short* __restrict__ wbt,   // [SN][64][KB] bf16
    const float* __restrict__ bias,           // [SN*64] f32
    unsigned short* __restrict__ ob,          // bf16 out (ELU path)
    float* __restrict__ of)                   // f32 out
{
    constexpr int KG = 32;
    constexpr int G  = KB / KG;
    constexpr int IW = KB * 64;
    constexpr int OW = SN * 64;

    const int tid  = threadIdx.x;
    const int lane = tid & 63;
    const int wave = tid >> 6;
    const int l15  = lane & 15;
    const int l4   = lane >> 4;
    const int rt   = wave >> 2;
    const int wq   = wave & 3;
    const int r0   = blockIdx.x * 32;
    const int s0   = blockIdx.y * 16;

    // [row][s(17)][kbl(36)]: row stride 612 u16 (306 b32, 306%32=18 -> 16-bank
    // spread), b64 reads at floor, paired b32 writes 4-way.
    __shared__ __align__(16) unsigned short y0s[32][17][36];

    floatx4 accB[16];
#pragma unroll
    for (int s = 0; s < 16; ++s) accB[s] = (floatx4){0.f, 0.f, 0.f, 0.f};

    const int arow = r0 + rt * 16 + l15;

    for (int g = 0; g < G; ++g) {
        const int kb0 = g * KG + wq * 8;     // this wave's 8-kb stripe
        const unsigned short* aP  = xb ? xb + (size_t)arow * IW + kb0 * 64 + l4 * 8 : nullptr;
        const float*          aPf = xf ? xf + (size_t)arow * IW + kb0 * 64 + l4 * 8 : nullptr;
        const unsigned short* bP  = wat + ((size_t)kb0 * SN + s0 + l15) * 64 + l4 * 8;

#pragma unroll
        for (int tp = 0; tp < 4; ++tp) {
            const int t0 = tp * 2;           // tiles t0, t0+1 (kbl = wq*8 + t)
            short8 a00, a01, a10, a11;
            if constexpr (XBF16) {
                a00 = ld8(aP + t0 * 64);      a01 = ld8(aP + t0 * 64 + 32);
                a10 = ld8(aP + t0 * 64 + 64); a11 = ld8(aP + t0 * 64 + 96);
            } else {
#pragma unroll
                for (int h = 0; h < 4; ++h) {
                    const float* pp = aPf + t0 * 64 + h * 32;
                    floatx4 u0 = *reinterpret_cast<const floatx4*>(pp);
                    floatx4 u1 = *reinterpret_cast<const floatx4*>(pp + 4);
                    short8* dst = (h < 2) ? ((h & 1) ? &a01 : &a00)
                                          : ((h & 1) ? &a11 : &a10);
#pragma unroll
                    for (int i = 0; i < 4; ++i) {
                        (*dst)[i]     = (short)f2bf(u0[i]);
                        (*dst)[i + 4] = (short)f2bf(u1[i]);
                    }
                }
            }
            short8 b00 = ld8(bP + (size_t)t0 * SN * 64);
            short8 b01 = ld8(bP + (size_t)t0 * SN * 64 + 32);
            short8 b10 = ld8(bP + (size_t)(t0 + 1) * SN * 64);
            short8 b11 = ld8(bP + (size_t)(t0 + 1) * SN * 64 + 32);

            floatx4 acc0 = (floatx4){0.f, 0.f, 0.f, 0.f};
            floatx4 acc1 = (floatx4){0.f, 0.f, 0.f, 0.f};
            acc0 = __builtin_amdgcn_mfma_f32_16x16x32_bf16(a00, b00, acc0, 0, 0, 0);
            acc0 = __builtin_amdgcn_mfma_f32_16x16x32_bf16(a01, b01, acc0, 0, 0, 0);
            acc1 = __builtin_amdgcn_mfma_f32_16x16x32_bf16(a10, b10, acc1, 0, 0, 0);
            acc1 = __builtin_amdgcn_mfma_f32_16x16x32_bf16(a11, b11, acc1, 0, 0, 0);

            // pack rows: (kbl even, kbl+1) -> one b32 store
#pragma unroll
            for (int rg = 0; rg < 4; ++rg) {
                unsigned int pk = (unsigned int)f2bf(acc0[rg]) |
                                  ((unsigned int)f2bf(acc1[rg]) << 16);
                *reinterpret_cast<unsigned int*>(
                    &y0s[rt * 16 + l4 * 4 + rg][l15][wq * 8 + t0]) = pk;
            }
        }
        __syncthreads();

        const unsigned short* wbP =
            wbt + ((size_t)s0 * 64 + wq * 16 + l15) * KB + g * KG + l4 * 8;
#pragma unroll
        for (int s = 0; s < 16; ++s) {
            short4v x0 = *reinterpret_cast<const short4v*>(&y0s[rt * 16 + l15][s][l4 * 8]);
            short4v x1 = *reinterpret_cast<const short4v*>(&y0s[rt * 16 + l15][s][l4 * 8 + 4]);
            short8 af = {x0[0], x0[1], x0[2], x0[3], x1[0], x1[1], x1[2], x1[3]};
            short8 bf = ld8(wbP + (size_t)s * 64 * KB);
            accB[s] = __builtin_amdgcn_mfma_f32_16x16x32_bf16(af, bf, accB[s], 0, 0, 0);
        }
        __syncthreads();
    }

    // epilogue: bias (+ELU) and store
#pragma unroll
    for (int s = 0; s < 16; ++s) {
        const int col = (s0 + s) * 64 + wq * 16 + l15;
        const float bv = bias[col];
#pragma unroll
        for (int rg = 0; rg < 4; ++rg) {
            const int row = r0 + rt * 16 + l4 * 4 + rg;
            float v = accB[s][rg] + bv;
            if constexpr (ELU) {
                v = v > 0.f ? v : expm1f(v);
                ob[(size_t)row * OW + col] = f2bf(v);
            } else {
                of[(size_t)row * OW + col] = v;
            }
        }
    }
}

extern "C" void kernel_launch(void* const* d_in, const int* in_sizes, int n_in,
                              void* d_out, int out_size, void* d_ws, size_t ws_size,
                              hipStream_t stream) {
    const float* x  = (const float*)d_in[0];
    const float* w0 = (const float*)d_in[1];
    const float* w1 = (const float*)d_in[2];
    const float* b1 = (const float*)d_in[3];
    const float* w2 = (const float*)d_in[4];
    const float* w3 = (const float*)d_in[5];
    const float* b3 = (const float*)d_in[6];
    float* out = (float*)d_out;

    const int bs = in_sizes[0] / 4096;

    // ws layout (u16): z[bs*8192] | w0t | w1t | w2t | w3t | xb[bs*4096]
    unsigned short* z   = (unsigned short*)d_ws;
    const size_t zElems = (size_t)bs * 8192;
    unsigned short* w0t = z + zElems;
    unsigned short* w1t = w0t + 64 * 128 * 64;
    unsigned short* w2t = w1t + 128 * 64 * 64;
    unsigned short* w3t = w2t + 128 * 64 * 64;
    unsigned short* xb  = w3t + 64 * 128 * 64;
    const size_t need1 = (zElems + 4ull * 524288) * sizeof(unsigned short);
    const size_t need2 = need1 + (size_t)bs * 4096 * sizeof(unsigned short);
    if (n_in < 7 || (bs & 31) || ws_size < need1) return;
    const bool useXb = (ws_size >= need2);

    transpose_cast_k<<<dim3(512), dim3(256), 0, stream>>>(w0, w0t, 64, 64, 128);
    transpose_cast_k<<<dim3(512), dim3(256), 0, stream>>>(w1, w1t, 128, 64, 64);
    transpose_cast_k<<<dim3(512), dim3(256), 0, stream>>>(w2, w2t, 128, 64, 64);
    transpose_cast_k<<<dim3(512), dim3(256), 0, stream>>>(w3, w3t, 64, 128, 64);

    if (useXb) {
        cast_x_bf16<<<dim3(4096), dim3(256), 0, stream>>>(x, xb, bs * 4096 / 8);
        fused2<64, 128, true, true><<<dim3(bs / 32, 8), dim3(512), 0, stream>>>(
            nullptr, xb, w0t, w1t, b1, z, nullptr);
    } else {
        fused2<64, 128, true, false><<<dim3(bs / 32, 8), dim3(512), 0, stream>>>(
            x, nullptr, w0t, w1t, b1, z, nullptr);
    }
    fused2<128, 64, false, true><<<dim3(bs / 32, 4), dim3(512), 0, stream>>>(
        nullptr, z, w2t, w3t, b3, nullptr, out);
}

// Round 3
// 471.931 us; speedup vs baseline: 1.3134x; 1.3134x over previous
//
#include <hip/hip_runtime.h>
#include <hip/hip_bf16.h>

// Monarch block-MLP, bf16 MFMA, fp32 accumulate. Round 3:
// m97 structure: global_load_lds DMA double-buffer for the streamed operand,
// M=16 rows/wg + 55KB LDS -> 2 blocks/CU so the barrier's vmcnt-drain is
// hidden by the co-resident block. Weights direct global->reg (L2-resident).

typedef __attribute__((ext_vector_type(8))) short short8;
typedef __attribute__((ext_vector_type(4))) float floatx4;

__device__ __forceinline__ unsigned short f2bf(float f) {
    unsigned int u = __float_as_uint(f);
    unsigned int r = 0x7FFFu + ((u >> 16) & 1u);
    return (unsigned short)((u + r) >> 16);
}
__device__ __forceinline__ short8 ld8(const unsigned short* p) {
    return *reinterpret_cast<const short8*>(p);
}
__device__ __forceinline__ void gload_lds16(const void* g, void* l) {
    __builtin_amdgcn_global_load_lds(
        (const __attribute__((address_space(1))) unsigned int*)g,
        (__attribute__((address_space(3))) unsigned int*)l, 16, 0, 0);
}

__global__ void cast_x_bf16(const float* __restrict__ in,
                            unsigned short* __restrict__ out, int n8) {
    int stride = gridDim.x * blockDim.x;
    for (int idx = blockIdx.x * blockDim.x + threadIdx.x; idx < n8; idx += stride) {
        const float* p = in + (size_t)idx * 8;
        floatx4 f0 = *reinterpret_cast<const floatx4*>(p);
        floatx4 f1 = *reinterpret_cast<const floatx4*>(p + 4);
        short8 o;
#pragma unroll
        for (int j = 0; j < 4; ++j) {
            o[j]     = (short)f2bf(f0[j]);
            o[j + 4] = (short)f2bf(f1[j]);
        }
        *reinterpret_cast<short8*>(out + (size_t)idx * 8) = o;
    }
}

// out[b][c][r] = bf16(in[b][r][c])
__global__ void transpose_cast_k(const float* __restrict__ in,
                                 unsigned short* __restrict__ out,
                                 int Bn, int R, int C) {
    int total = Bn * R * C;
    int stride = gridDim.x * blockDim.x;
    for (int idx = blockIdx.x * blockDim.x + threadIdx.x; idx < total; idx += stride) {
        int rc = R * C;
        int b = idx / rc;
        int rem = idx - b * rc;
        int c = rem / R;
        int r = rem - c * R;
        out[idx] = f2bf(in[(size_t)(b * R + r) * C + c]);
    }
}

// MFMA 16x16x32 bf16 layouts (m89-verified):
//   A: row = lane&15, k = (lane>>4)*8 + i ;  B: col = lane&15, same k
//   D: col = lane&15, row = (lane>>4)*4 + reg
//
// Per wg: M=16 rows, SC=16 s, 8 waves. k-group = 32 kb (stage-B MFMA K=32),
// DMA'd in 4 sub-chunks of 8 kb (1 KB/row each = 1 DMA instr/row).
template<int KB, int SN, bool ELU>
__global__ __launch_bounds__(512, 4) void fused3(
    const unsigned short* __restrict__ xb,    // [bs][KB*64] bf16
    const unsigned short* __restrict__ wat,   // [KB][SN][64] bf16
    const unsigned short* __restrict__ wbt,   // [SN][64][KB] bf16
    const float* __restrict__ bias,           // [SN*64]
    unsigned short* __restrict__ ob,          // bf16 out (ELU path)
    float* __restrict__ of)                   // f32 out
{
    constexpr int G    = KB / 32;
    constexpr int NSUB = G * 4;
    constexpr int IW   = KB * 64;
    constexpr int OW   = SN * 64;
    constexpr int XROW = 520;                 // elems; 1040 B row stride (16B-mult)

    const int tid  = threadIdx.x;
    const int lane = tid & 63;
    const int wave = tid >> 6;                // 0..7
    const int l15  = lane & 15;
    const int l4   = lane >> 4;               // 0..3
    const int r0   = blockIdx.x * 16;
    const int s0   = blockIdx.y * 16;

    // xs: streamed-operand sub-chunk, double buffered (33.3 KB)
    __shared__ __align__(16) unsigned short xs[2][16 * XROW];
    // y0s[row][s(17)][kb(40)]: 21.8 KB; all b128 strides 16B-aligned
    __shared__ __align__(16) unsigned short y0s[16][17][40];

    floatx4 acc[8];
#pragma unroll
    for (int j = 0; j < 8; ++j) acc[j] = (floatx4){0.f, 0.f, 0.f, 0.f};

    // DMA sub-chunk c into xs[c&1]: rows 2*wave, 2*wave+1 (wave-uniform dest)
    auto dma = [&](int c) {
        const int buf = c & 1;
#pragma unroll
        for (int i = 0; i < 2; ++i) {
            const int r = wave * 2 + i;
            gload_lds16(xb + (size_t)(r0 + r) * IW + c * 512 + lane * 8,
                        &xs[buf][r * XROW]);
        }
    };

    dma(0);
    int c = 0;
    for (int g = 0; g < G; ++g) {
#pragma unroll
        for (int sc = 0; sc < 4; ++sc, ++c) {
            __syncthreads();   // drains DMA(c); also y0s(B-read)/A-write fence
            const int kbl = sc * 8 + wave;        // kb index within group, 0..31
            const int kb  = g * 32 + kbl;
            const unsigned short* xrow = &xs[c & 1][l15 * XROW + wave * 64 + l4 * 8];
            const unsigned short* wp   = wat + ((size_t)kb * SN + s0 + l15) * 64 + l4 * 8;
            short8 a0 = ld8(xrow);
            short8 a1 = ld8(xrow + 32);
            short8 b0 = ld8(wp);
            short8 b1 = ld8(wp + 32);
            floatx4 t = (floatx4){0.f, 0.f, 0.f, 0.f};
            t = __builtin_amdgcn_mfma_f32_16x16x32_bf16(a0, b0, t, 0, 0, 0);
            t = __builtin_amdgcn_mfma_f32_16x16x32_bf16(a1, b1, t, 0, 0, 0);
#pragma unroll
            for (int rg = 0; rg < 4; ++rg)
                y0s[l4 * 4 + rg][l15][kbl] = f2bf(t[rg]);
            if (c + 1 < NSUB) dma(c + 1);
        }
        __syncthreads();       // y0s complete for this group

        // stage B: per wave 2 s-values, 8 j-tiles; K=32 over this group's kb
        short8 afA = ld8(&y0s[l15][wave * 2 + 0][l4 * 8]);
        short8 afB = ld8(&y0s[l15][wave * 2 + 1][l4 * 8]);
        const unsigned short* wbP =
            wbt + ((size_t)(s0 + wave * 2) * 64 + l15) * KB + g * 32 + l4 * 8;
#pragma unroll
        for (int jj = 0; jj < 8; ++jj) {
            const int sh = jj >> 2;            // 0/1 -> s = wave*2+sh
            const int jq = jj & 3;
            short8 bf = ld8(wbP + ((size_t)sh * 64 + jq * 16) * KB);
            acc[jj] = __builtin_amdgcn_mfma_f32_16x16x32_bf16(
                sh ? afB : afA, bf, acc[jj], 0, 0, 0);
        }
    }

    // epilogue
#pragma unroll
    for (int jj = 0; jj < 8; ++jj) {
        const int s   = wave * 2 + (jj >> 2);
        const int col = (s0 + s) * 64 + (jj & 3) * 16 + l15;
        const float bv = bias[col];
#pragma unroll
        for (int rg = 0; rg < 4; ++rg) {
            const int row = r0 + l4 * 4 + rg;
            float v = acc[jj][rg] + bv;
            if constexpr (ELU) {
                v = v > 0.f ? v : expm1f(v);
                ob[(size_t)row * OW + col] = f2bf(v);
            } else {
                of[(size_t)row * OW + col] = v;
            }
        }
    }
}

extern "C" void kernel_launch(void* const* d_in, const int* in_sizes, int n_in,
                              void* d_out, int out_size, void* d_ws, size_t ws_size,
                              hipStream_t stream) {
    const float* x  = (const float*)d_in[0];
    const float* w0 = (const float*)d_in[1];
    const float* w1 = (const float*)d_in[2];
    const float* b1 = (const float*)d_in[3];
    const float* w2 = (const float*)d_in[4];
    const float* w3 = (const float*)d_in[5];
    const float* b3 = (const float*)d_in[6];
    float* out = (float*)d_out;

    const int bs = in_sizes[0] / 4096;

    // ws (u16): z[bs*8192] | w0t | w1t | w2t | w3t | xb[bs*4096]
    unsigned short* z   = (unsigned short*)d_ws;
    const size_t zElems = (size_t)bs * 8192;
    unsigned short* w0t = z + zElems;
    unsigned short* w1t = w0t + 64 * 128 * 64;
    unsigned short* w2t = w1t + 128 * 64 * 64;
    unsigned short* w3t = w2t + 128 * 64 * 64;
    unsigned short* xb  = w3t + 64 * 128 * 64;
    const size_t need1 = (zElems + 4ull * 524288) * sizeof(unsigned short);
    const size_t need2 = need1 + (size_t)bs * 4096 * sizeof(unsigned short);
    if (n_in < 7 || (bs & 15) || ws_size < need1) return;
    if (ws_size < need2) {
        // xb lives in d_out (dead before K2 writes out); out_size*4 >= bs*4096*2
        xb = (unsigned short*)d_out;
    }

    transpose_cast_k<<<dim3(512), dim3(256), 0, stream>>>(w0, w0t, 64, 64, 128);
    transpose_cast_k<<<dim3(512), dim3(256), 0, stream>>>(w1, w1t, 128, 64, 64);
    transpose_cast_k<<<dim3(512), dim3(256), 0, stream>>>(w2, w2t, 128, 64, 64);
    transpose_cast_k<<<dim3(512), dim3(256), 0, stream>>>(w3, w3t, 64, 128, 64);
    cast_x_bf16<<<dim3(2048), dim3(256), 0, stream>>>(x, xb, bs * 4096 / 8);

    fused3<64, 128, true><<<dim3(bs / 16, 8), dim3(512), 0, stream>>>(
        xb, w0t, w1t, b1, z, nullptr);
    fused3<128, 64, false><<<dim3(bs / 16, 4), dim3(512), 0, stream>>>(
        z, w2t, w3t, b3, nullptr, out);
}